// Round 2
// baseline (382.282 us; speedup 1.0000x reference)
//
#include <hip/hip_runtime.h>
#include <hip/hip_bf16.h>

// y = x @ P,  P = gamma * (w_q w_k^T) (x^T x) w_v      (no softmax => associativity)
// All GEMMs in one "NT" form: C[m][n] = scale * sum_k A[m][k] * B[n][k]
// m97-ladder structure: 128x128 tile, BK=32, unpadded LDS, global_load_lds width=16.

typedef __attribute__((ext_vector_type(8))) short bf16x8;   // 8 x bf16 (4 VGPRs)
typedef __attribute__((ext_vector_type(4))) float f32x4;    // 4 x fp32 accum

#define BM 128
#define BN 128
#define BK 32

// async global->LDS, 16B per lane. LDS dest is wave-uniform base + lane*16;
// we pass per-lane ptr consistent with that mapping (lane0's ptr == base).
__device__ __forceinline__ void gl_lds16(const void* g, void* l) {
    __builtin_amdgcn_global_load_lds(
        (const __attribute__((address_space(1))) unsigned int*)g,
        (__attribute__((address_space(3))) unsigned int*)l, 16, 0, 0);
}

template<bool A_F32, bool OUT_F32>
__global__ __launch_bounds__(256)
void gemm_nt(const void* __restrict__ Ap, const __hip_bfloat16* __restrict__ Bp,
             void* __restrict__ Cp, int N, int K,
             long sA, long sB, long sC, float scale)
{
    __shared__ __hip_bfloat16 At[BM * BK];   // [128][32] row-major, NO padding
    __shared__ __hip_bfloat16 Bt[BN * BK];

    const int bz = blockIdx.z;
    const int n0 = blockIdx.x * BN;
    const int m0 = blockIdx.y * BM;

    const int tid  = threadIdx.x;
    const int lane = tid & 63;
    const int wave = tid >> 6;
    const int wm = (wave & 1) * 64;   // wave's 64x64 quadrant
    const int wn = (wave >> 1) * 64;
    const int l16 = lane & 15;
    const int lq  = lane >> 4;        // 0..3

    const __hip_bfloat16* Bb = Bp + (size_t)bz * sB;

    f32x4 acc[4][4] = {};

    // 16B chunk id for staging: chunk c -> row=c>>2, kcol=(c&3)*8
    const int cBase = wave * 64 + lane;   // 0..255

    for (int k0 = 0; k0 < K; k0 += BK) {
        if (A_F32) {
            // fp32 -> bf16 cast-on-fly staging (128x32 fp32 = 1024 float4 chunks)
            const float* Ab = (const float*)Ap + (size_t)bz * sA;
            #pragma unroll
            for (int i = 0; i < 4; ++i) {
                const int c = i * 256 + tid;        // float4 chunk id
                const int row = c >> 3, kc = (c & 7) * 4;
                float4 f = *(const float4*)(Ab + (size_t)(m0 + row) * K + k0 + kc);
                union { __hip_bfloat16 h[4]; unsigned long long u; } t;
                t.h[0] = __float2bfloat16(f.x); t.h[1] = __float2bfloat16(f.y);
                t.h[2] = __float2bfloat16(f.z); t.h[3] = __float2bfloat16(f.w);
                *(unsigned long long*)&At[row * BK + kc] = t.u;   // ds_write_b64, bank-clean
            }
        } else {
            const __hip_bfloat16* Ab = (const __hip_bfloat16*)Ap + (size_t)bz * sA;
            #pragma unroll
            for (int i = 0; i < 2; ++i) {
                const int c = i * 256 + cBase;
                const int row = c >> 2, kc = (c & 3) * 8;
                gl_lds16(Ab + (size_t)(m0 + row) * K + k0 + kc, &At[c * 8]);
            }
        }
        #pragma unroll
        for (int i = 0; i < 2; ++i) {
            const int c = i * 256 + cBase;
            const int row = c >> 2, kc = (c & 3) * 8;
            gl_lds16(Bb + (size_t)(n0 + row) * K + k0 + kc, &Bt[c * 8]);
        }
        __syncthreads();   // drains vmcnt (global_load_lds) + lgkmcnt

        bf16x8 af[4], bfr[4];
        #pragma unroll
        for (int i = 0; i < 4; ++i)
            af[i] = *(const bf16x8*)&At[(wm + i * 16 + l16) * BK + lq * 8];
        #pragma unroll
        for (int j = 0; j < 4; ++j)
            bfr[j] = *(const bf16x8*)&Bt[(wn + j * 16 + l16) * BK + lq * 8];
        #pragma unroll
        for (int i = 0; i < 4; ++i)
            #pragma unroll
            for (int j = 0; j < 4; ++j)
                acc[i][j] = __builtin_amdgcn_mfma_f32_16x16x32_bf16(af[i], bfr[j], acc[i][j], 0, 0, 0);
        __syncthreads();
    }

    // epilogue: C/D layout col=lane&15, row=(lane>>4)*4+reg (m89/m91-verified)
    float* Cf = (float*)Cp;
    __hip_bfloat16* Ch = (__hip_bfloat16*)Cp;
    #pragma unroll
    for (int i = 0; i < 4; ++i) {
        #pragma unroll
        for (int j = 0; j < 4; ++j) {
            const int row0 = m0 + wm + i * 16 + lq * 4;
            const int col  = n0 + wn + j * 16 + l16;
            #pragma unroll
            for (int r = 0; r < 4; ++r) {
                float v = acc[i][j][r] * scale;
                size_t idx = (size_t)bz * sC + (size_t)(row0 + r) * N + col;
                if (OUT_F32) Cf[idx] = v;
                else         Ch[idx] = __float2bfloat16(v);
            }
        }
    }
}

// Tiled transpose + fp32->bf16 cast: in (R x C) fp32 row-major -> out (C x R) bf16
#define TP 64
__global__ __launch_bounds__(256)
void transpose_cast(const float* __restrict__ in, __hip_bfloat16* __restrict__ out,
                    int R, int C, long inStride, long outStride)
{
    __shared__ __hip_bfloat16 tile[TP][TP + 2];
    const int b  = blockIdx.z;
    const int r0 = blockIdx.x * TP;
    const int c0 = blockIdx.y * TP;
    const float* inb = in + (size_t)b * inStride;
    __hip_bfloat16* outb = out + (size_t)b * outStride;
    const int tx = threadIdx.x;   // 0..63
    const int ty = threadIdx.y;   // 0..3
    #pragma unroll
    for (int r = 0; r < TP; r += 4) {
        const int row = r + ty;
        tile[row][tx] = __float2bfloat16(inb[(size_t)(r0 + row) * C + c0 + tx]);
    }
    __syncthreads();
    #pragma unroll
    for (int r = 0; r < TP; r += 4) {
        const int row = r + ty;
        outb[(size_t)(c0 + row) * R + r0 + tx] = tile[tx][row];
    }
}

__global__ __launch_bounds__(256)
void cast_f32_bf16(const float* __restrict__ in, __hip_bfloat16* __restrict__ out, int n)
{
    const int i = (blockIdx.x * 256 + threadIdx.x) << 2;
    if (i >= n) return;
    float4 f = *(const float4*)(in + i);
    union { __hip_bfloat16 h[4]; uint2 u; } t;
    t.h[0] = __float2bfloat16(f.x); t.h[1] = __float2bfloat16(f.y);
    t.h[2] = __float2bfloat16(f.z); t.h[3] = __float2bfloat16(f.w);
    *(uint2*)(out + i) = t.u;
}

extern "C" void kernel_launch(void* const* d_in, const int* in_sizes, int n_in,
                              void* d_out, int out_size, void* d_ws, size_t ws_size,
                              hipStream_t stream)
{
    const int Bz = 4, T = 4096, D = 1024;
    const float gamma = 32.0f;  // sqrt(1024)

    const float* x  = (const float*)d_in[0];
    const float* wq = (const float*)d_in[1];
    const float* wk = (const float*)d_in[2];
    const float* wv = (const float*)d_in[3];
    float* y = (float*)d_out;

    // workspace layout (32 MB total)
    unsigned char* p = (unsigned char*)d_ws;
    const size_t DD = (size_t)D * D;
    __hip_bfloat16* Gb  = (__hip_bfloat16*)p; p += Bz * DD * 2;   //  8 MB  G_b = x_b^T x_b
    __hip_bfloat16* Hb  = (__hip_bfloat16*)p; p += Bz * DD * 2;   //  8 MB  H_b = C0 G_b
    __hip_bfloat16* PTb = (__hip_bfloat16*)p; p += Bz * DD * 2;   //  8 MB  P_b^T
    __hip_bfloat16* wqb = (__hip_bfloat16*)p; p += DD * 2;        //  2 MB
    __hip_bfloat16* wkb = (__hip_bfloat16*)p; p += DD * 2;        //  2 MB
    __hip_bfloat16* wvT = (__hip_bfloat16*)p; p += DD * 2;        //  2 MB  w_v^T
    __hip_bfloat16* C0b = (__hip_bfloat16*)p; p += DD * 2;        //  2 MB  w_q w_k^T
    // x^T (bf16, B x D x T = 32 MB) staged in d_out's first half; consumed by the
    // G GEMM, then fully overwritten by the final y GEMM.
    __hip_bfloat16* xbT = (__hip_bfloat16*)d_out;

    dim3 blk(256);

    cast_f32_bf16<<<dim3((int)(DD / 1024)), blk, 0, stream>>>(wq, wqb, (int)DD);
    cast_f32_bf16<<<dim3((int)(DD / 1024)), blk, 0, stream>>>(wk, wkb, (int)DD);
    transpose_cast<<<dim3(D / TP, D / TP, 1), dim3(64, 4), 0, stream>>>(wv, wvT, D, D, 0, 0);
    transpose_cast<<<dim3(T / TP, D / TP, Bz), dim3(64, 4), 0, stream>>>(
        x, xbT, T, D, (long)T * D, (long)D * T);

    // C0 = w_q w_k^T                      : NT(A=wq, B=wk)
    gemm_nt<false, false><<<dim3(D / BN, D / BM, 1), blk, 0, stream>>>(
        wqb, wkb, C0b, D, D, 0, 0, 0, 1.0f);
    // G_b = x_b^T x_b                     : NT(A=xbT, B=xbT), K = T
    gemm_nt<false, false><<<dim3(D / BN, D / BM, Bz), blk, 0, stream>>>(
        xbT, xbT, Gb, D, T, (long)D * T, (long)D * T, (long)DD, 1.0f);
    // H_b = C0 G_b  (G symmetric)         : NT(A=C0, B=G)
    gemm_nt<false, false><<<dim3(D / BN, D / BM, Bz), blk, 0, stream>>>(
        C0b, Gb, Hb, D, D, 0, (long)DD, (long)DD, 1.0f);
    // P_b^T = gamma * w_v^T H_b^T         : NT(A=wvT, B=H)  [C^T = NT(B,A)]
    gemm_nt<false, false><<<dim3(D / BN, D / BM, Bz), blk, 0, stream>>>(
        wvT, Hb, PTb, D, D, 0, (long)DD, (long)DD, gamma);
    // y_b = x_b P_b                       : NT(A=x fp32, B=P^T), out fp32
    gemm_nt<true, true><<<dim3(D / BN, T / BM, Bz), blk, 0, stream>>>(
        x, PTb, y, D, D, (long)T * D, (long)DD, (long)T * D, 1.0f);
}